// Round 13
// baseline (85.171 us; speedup 1.0000x reference)
//
#include <hip/hip_runtime.h>
#include <hip/hip_bf16.h>

#define N_TOK 16384
#define B_DIM 8
#define C_DIM 256
#define M_ROWS (N_TOK * B_DIM)   // 131072
#define BM 32

typedef __attribute__((ext_vector_type(8))) short short8;
typedef __attribute__((ext_vector_type(4))) float f32x4;

__device__ __forceinline__ unsigned short f2bf(float f) {
    union { float f; unsigned u; } v; v.f = f;
    unsigned r = v.u + 0x7fffu + ((v.u >> 16) & 1u);  // RNE
    return (unsigned short)(r >> 16);
}

__device__ __forceinline__ float bf2f(unsigned short h) {
    union { unsigned u; float f; } v; v.u = ((unsigned)h) << 16;
    return v.f;
}

// packed RNE f32x2 -> bf16x2 (low = a, high = b)
__device__ __forceinline__ unsigned cvt_pk(float a, float b) {
    unsigned r;
    asm("v_cvt_pk_bf16_f32 %0, %1, %2" : "=v"(r) : "v"(a), "v"(b));
    return r;
}

// Kernel A: m -> d_out tail; W fp32 -> bf16 in MFMA-fragment order.
// Wf[((ctile*8 + k8)*64 + lane)*8 + r] = bf16(W[ctile*16 + (lane&15)][k8*32 + (lane>>4)*8 + r])
__global__ __launch_bounds__(256)
void prep_kernel(const int* __restrict__ mask, const int* __restrict__ fg,
                 const float* __restrict__ W, unsigned short* __restrict__ Wf,
                 float* __restrict__ m_out) {
    int i = blockIdx.x * 256 + threadIdx.x;
    if (i < C_DIM * C_DIM) {
        int d = i >> 8;            // W row = output col
        int c = i & 255;           // k
        int ctile = d >> 4;
        int k8    = c >> 5;
        int lane  = ((c >> 3) & 3) * 16 + (d & 15);
        int r     = c & 7;
        Wf[((ctile * 8 + k8) * 64 + lane) * 8 + r] = f2bf(W[i]);
    }
    if (i < M_ROWS) {
        int b = i & (B_DIM - 1);
        int n = i >> 3;
        m_out[i] = (fg[i] != 0) ? (1.0f - (float)mask[b * N_TOK + n]) : 0.0f;
    }
}

// Kernel B: round-8 structure + LDS-transposed epilogue (float4 stores).
__global__ __launch_bounds__(256, 3)
void mlp_kernel(const float* __restrict__ x, const unsigned short* __restrict__ Wf,
                const float* __restrict__ bias, const float* __restrict__ m,
                float* __restrict__ out) {
    __shared__ unsigned short lds_x[BM * C_DIM];   // 16 KB bf16, XOR-swizzled
    __shared__ float lds_res[BM * C_DIM];          // 32 KB fp32, XOR-swizzled
    __shared__ float lds_m[BM];

    const int t    = threadIdx.x;
    const int row0 = blockIdx.x * BM;

    // ---- Stage x tile (32 x 256 fp32 -> bf16 LDS), coalesced 32B/lane ----
    #pragma unroll
    for (int j = 0; j < 4; ++j) {
        int ci  = j * 256 + t;
        int row = ci >> 5;            // 0..31
        int cc  = (ci & 31) * 8;      // 0..248
        const float4* p = (const float4*)(x + (size_t)(row0 + row) * C_DIM + cc);
        float4 a0 = p[0];
        float4 a1 = p[1];
        int4 pk;
        pk.x = (int)cvt_pk(a0.x, a0.y);
        pk.y = (int)cvt_pk(a0.z, a0.w);
        pk.z = (int)cvt_pk(a1.x, a1.y);
        pk.w = (int)cvt_pk(a1.z, a1.w);
        int byte = (row * 512 + cc * 2) ^ ((row & 7) << 4);
        *(int4*)((char*)lds_x + byte) = pk;
    }
    if (t < BM) lds_m[t] = m[row0 + t];
    __syncthreads();

    // ---- MFMA: 4 waves x 64 cols, 2(row) x 4(col) 16x16 tiles each ----
    const int lane = t & 63;
    const int wid  = t >> 6;
    const int col0 = wid * 64;
    const int lr   = lane & 15;
    const int kb   = (lane >> 4) * 8;
    const int rsub = (lane >> 4) * 4;   // C/D: row = (lane>>4)*4 + reg

    f32x4 acc[2][4];
    #pragma unroll
    for (int i = 0; i < 2; ++i)
        #pragma unroll
        for (int j = 0; j < 4; ++j) acc[i][j] = (f32x4){0.f, 0.f, 0.f, 0.f};

    // Wave's fragment base: ctile = wid*4 + ct
    const short8* wfb = (const short8*)Wf + (size_t)wid * 4 * 8 * 64 + lane;

    short8 wcur[4], wnxt[4];
    #pragma unroll
    for (int ct = 0; ct < 4; ++ct)
        wcur[ct] = wfb[(ct * 8) * 64];            // k8 = 0, 1 KB coalesced/wave

    #pragma unroll
    for (int k8 = 0; k8 < 8; ++k8) {
        if (k8 < 7) {                              // 1-deep W prefetch from L2
            #pragma unroll
            for (int ct = 0; ct < 4; ++ct)
                wnxt[ct] = wfb[(ct * 8 + k8 + 1) * 64];
        }
        short8 af[2];
        #pragma unroll
        for (int rt = 0; rt < 2; ++rt) {
            int row  = rt * 16 + lr;
            int byte = (row * 512 + (k8 * 32 + kb) * 2) ^ ((row & 7) << 4);
            af[rt] = *(const short8*)((const char*)lds_x + byte);
        }
        #pragma unroll
        for (int rt = 0; rt < 2; ++rt)
            #pragma unroll
            for (int ct = 0; ct < 4; ++ct)
                acc[rt][ct] = __builtin_amdgcn_mfma_f32_16x16x32_bf16(
                    af[rt], wcur[ct], acc[rt][ct], 0, 0, 0);
        #pragma unroll
        for (int ct = 0; ct < 4; ++ct) wcur[ct] = wnxt[ct];
    }

    // ---- Epilogue phase 1: relu(acc+b) -> lds_res (2-way conflicts: free) ----
    float bv[4];
    #pragma unroll
    for (int ct = 0; ct < 4; ++ct) bv[ct] = bias[col0 + ct * 16 + lr];

    #pragma unroll
    for (int rt = 0; rt < 2; ++rt) {
        #pragma unroll
        for (int r = 0; r < 4; ++r) {
            int lrow = rt * 16 + rsub + r;
            int swz  = (lrow & 7) << 4;
            #pragma unroll
            for (int ct = 0; ct < 4; ++ct) {
                int col = col0 + ct * 16 + lr;
                float y = fmaxf(acc[rt][ct][r] + bv[ct], 0.0f);
                int byte = lrow * 1024 + ((col * 4) ^ swz);
                *(float*)((char*)lds_res + byte) = y;
            }
        }
    }
    __syncthreads();

    // ---- Epilogue phase 2: row-major gather, select, float4 stores ----
    {
        const int row = t >> 3;            // 0..31
        const int cg  = t & 7;             // col group: cols cg*32 .. +31
        const int swz = (row & 7) << 4;
        const float mv = lds_m[row];
        const int rbase = row * 1024;
        const int xbase = row * 512;

        float4 o[8];
        #pragma unroll
        for (int c = 0; c < 8; ++c)
            o[c] = *(const float4*)((const char*)lds_res +
                     (rbase + ((cg * 128 + c * 16) ^ swz)));

        if (mv == 0.0f) {                  // copy row: take x (bf16 round-trip)
            #pragma unroll
            for (int c8 = 0; c8 < 4; ++c8) {
                short8 xs = *(const short8*)((const char*)lds_x +
                             (xbase + ((cg * 64 + c8 * 16) ^ swz)));
                float4 lo, hi;
                lo.x = bf2f((unsigned short)xs[0]); lo.y = bf2f((unsigned short)xs[1]);
                lo.z = bf2f((unsigned short)xs[2]); lo.w = bf2f((unsigned short)xs[3]);
                hi.x = bf2f((unsigned short)xs[4]); hi.y = bf2f((unsigned short)xs[5]);
                hi.z = bf2f((unsigned short)xs[6]); hi.w = bf2f((unsigned short)xs[7]);
                o[c8 * 2]     = lo;
                o[c8 * 2 + 1] = hi;
            }
        }

        float4* op = (float4*)(out + (size_t)(row0 + row) * C_DIM + cg * 32);
        #pragma unroll
        for (int c = 0; c < 8; ++c) op[c] = o[c];
    }
}

extern "C" void kernel_launch(void* const* d_in, const int* in_sizes, int n_in,
                              void* d_out, int out_size, void* d_ws, size_t ws_size,
                              hipStream_t stream) {
    const float* x    = (const float*)d_in[0];
    const int*   mask = (const int*)d_in[1];
    const int*   fg   = (const int*)d_in[2];
    const float* W    = (const float*)d_in[3];
    const float* b    = (const float*)d_in[4];

    float* out   = (float*)d_out;
    float* m_out = out + (size_t)M_ROWS * C_DIM;      // output 1: m (N,B)
    unsigned short* Wf = (unsigned short*)d_ws;       // 128 KB fragment-order W

    prep_kernel<<<M_ROWS / 256, 256, 0, stream>>>(mask, fg, W, Wf, m_out);
    mlp_kernel<<<M_ROWS / BM, 256, 0, stream>>>(x, Wf, b, m_out, out);
}

// Round 14
// 64.027 us; speedup vs baseline: 1.3302x; 1.3302x over previous
//
#include <hip/hip_runtime.h>
#include <hip/hip_bf16.h>

#define N_TOK 16384
#define B_DIM 8
#define C_DIM 256
#define M_ROWS (N_TOK * B_DIM)   // 131072
#define BM 32

typedef __attribute__((ext_vector_type(8))) short short8;
typedef __attribute__((ext_vector_type(4))) float f32x4;

__device__ __forceinline__ unsigned short f2bf(float f) {
    union { float f; unsigned u; } v; v.f = f;
    unsigned r = v.u + 0x7fffu + ((v.u >> 16) & 1u);  // RNE
    return (unsigned short)(r >> 16);
}

// packed RNE f32x2 -> bf16x2 (low = a, high = b)
__device__ __forceinline__ unsigned cvt_pk(float a, float b) {
    unsigned r;
    asm("v_cvt_pk_bf16_f32 %0, %1, %2" : "=v"(r) : "v"(a), "v"(b));
    return r;
}

__device__ __forceinline__ void gload_lds16(const void* g, void* l) {
    __builtin_amdgcn_global_load_lds(
        (const __attribute__((address_space(1))) void*)g,
        (__attribute__((address_space(3))) void*)l, 16, 0, 0);
}

// Kernel A: m -> d_out tail; W fp32 -> bf16 in MFMA-fragment order.
// Wf[((ctile*8 + k8)*64 + lane)*8 + r] = bf16(W[ctile*16 + (lane&15)][k8*32 + (lane>>4)*8 + r])
__global__ __launch_bounds__(256)
void prep_kernel(const int* __restrict__ mask, const int* __restrict__ fg,
                 const float* __restrict__ W, unsigned short* __restrict__ Wf,
                 float* __restrict__ m_out) {
    int i = blockIdx.x * 256 + threadIdx.x;
    if (i < C_DIM * C_DIM) {
        int d = i >> 8;            // W row = output col
        int c = i & 255;           // k
        int ctile = d >> 4;
        int k8    = c >> 5;
        int lane  = ((c >> 3) & 3) * 16 + (d & 15);
        int r     = c & 7;
        Wf[((ctile * 8 + k8) * 64 + lane) * 8 + r] = f2bf(W[i]);
    }
    if (i < M_ROWS) {
        int b = i & (B_DIM - 1);
        int n = i >> 3;
        m_out[i] = (fg[i] != 0) ? (1.0f - (float)mask[b * N_TOK + n]) : 0.0f;
    }
}

// Kernel B: r8 structure with global_load_lds DMA staging of fp32 x.
// Stage = 8 DMA instrs/wave (issue ~8 cy, zero VGPR/VALU held), wave parks at
// barrier; fp32->bf16 cvt moves into the k-loop (VALU was 88% idle); epilogue
// selects exact fp32 x from LDS. Content swizzle via inverse-swizzled global
// source + linear LDS dest (rule 21).
__global__ __launch_bounds__(256, 5)
void mlp_kernel(const float* __restrict__ x, const unsigned short* __restrict__ Wf,
                const float* __restrict__ bias, const float* __restrict__ m,
                float* __restrict__ out) {
    __shared__ float lds[BM * C_DIM];   // 32 KB fp32, XOR-swizzled content

    const int t    = threadIdx.x;
    const int row0 = blockIdx.x * BM;
    const int lane = t & 63;
    const int wid  = t >> 6;

    // ---- Stage: wave wid DMAs rows [wid*8, wid*8+8); 1 KB per instr ----
    {
        const char* xb = (const char*)(x + (size_t)row0 * C_DIM);
        #pragma unroll
        for (int r = 0; r < 8; ++r) {
            int row = wid * 8 + r;
            gload_lds16(xb + row * 1024 + ((lane * 16) ^ ((row & 7) << 4)),
                        (char*)lds + row * 1024);
        }
    }
    __syncthreads();   // drains the 8 DMAs (vmcnt) + nothing else outstanding

    // ---- MFMA: 4 waves x 64 cols, 2(row) x 4(col) 16x16 tiles each ----
    const int col0 = wid * 64;
    const int lr   = lane & 15;
    const int kb   = (lane >> 4) * 8;      // k-offset in floats
    const int rsub = (lane >> 4) * 4;      // C/D: row = (lane>>4)*4 + reg
    const char* Lc = (const char*)lds;

    f32x4 acc[2][4];
    #pragma unroll
    for (int i = 0; i < 2; ++i)
        #pragma unroll
        for (int j = 0; j < 4; ++j) acc[i][j] = (f32x4){0.f, 0.f, 0.f, 0.f};

    // Wave's fragment base: ctile = wid*4 + ct
    const short8* wfb = (const short8*)Wf + (size_t)wid * 4 * 8 * 64 + lane;

    short8 wcur[4], wnxt[4];
    #pragma unroll
    for (int ct = 0; ct < 4; ++ct)
        wcur[ct] = wfb[(ct * 8) * 64];            // k8 = 0, 1 KB coalesced/wave

    #pragma unroll
    for (int k8 = 0; k8 < 8; ++k8) {
        if (k8 < 7) {                              // 1-deep W prefetch from L2
            #pragma unroll
            for (int ct = 0; ct < 4; ++ct)
                wnxt[ct] = wfb[(ct * 8 + k8 + 1) * 64];
        }
        short8 af[2];
        #pragma unroll
        for (int rt = 0; rt < 2; ++rt) {
            int row  = rt * 16 + lr;
            int sz   = (row & 7) << 4;
            int base = row * 1024 + (k8 * 32 + kb) * 4;
            f32x4 f0 = *(const f32x4*)(Lc + (base ^ sz));
            f32x4 f1 = *(const f32x4*)(Lc + ((base + 16) ^ sz));
            int4 pk;
            pk.x = (int)cvt_pk(f0.x, f0.y);
            pk.y = (int)cvt_pk(f0.z, f0.w);
            pk.z = (int)cvt_pk(f1.x, f1.y);
            pk.w = (int)cvt_pk(f1.z, f1.w);
            af[rt] = *(const short8*)&pk;
        }
        #pragma unroll
        for (int rt = 0; rt < 2; ++rt)
            #pragma unroll
            for (int ct = 0; ct < 4; ++ct)
                acc[rt][ct] = __builtin_amdgcn_mfma_f32_16x16x32_bf16(
                    af[rt], wcur[ct], acc[rt][ct], 0, 0, 0);
        #pragma unroll
        for (int ct = 0; ct < 4; ++ct) wcur[ct] = wnxt[ct];
    }

    // ---- Epilogue: relu(acc+b), select vs EXACT fp32 x from LDS, store ----
    float bv[4];
    #pragma unroll
    for (int ct = 0; ct < 4; ++ct) bv[ct] = bias[col0 + ct * 16 + lr];

    #pragma unroll
    for (int rt = 0; rt < 2; ++rt) {
        float4 mreg = *(const float4*)(m + row0 + rt * 16 + rsub);
        #pragma unroll
        for (int r = 0; r < 4; ++r) {
            int lrow = rt * 16 + rsub + r;
            int sz   = (lrow & 7) << 4;
            float mv = (r == 0) ? mreg.x : (r == 1) ? mreg.y
                     : (r == 2) ? mreg.z : mreg.w;
            size_t grow = (size_t)row0 + lrow;
            #pragma unroll
            for (int ct = 0; ct < 4; ++ct) {
                int col = col0 + ct * 16 + lr;
                float y  = fmaxf(acc[rt][ct][r] + bv[ct], 0.0f);
                float xv = *(const float*)(Lc + ((lrow * 1024 + col * 4) ^ sz));
                out[grow * C_DIM + col] = (mv != 0.0f) ? y : xv;
            }
        }
    }
}

extern "C" void kernel_launch(void* const* d_in, const int* in_sizes, int n_in,
                              void* d_out, int out_size, void* d_ws, size_t ws_size,
                              hipStream_t stream) {
    const float* x    = (const float*)d_in[0];
    const int*   mask = (const int*)d_in[1];
    const int*   fg   = (const int*)d_in[2];
    const float* W    = (const float*)d_in[3];
    const float* b    = (const float*)d_in[4];

    float* out   = (float*)d_out;
    float* m_out = out + (size_t)M_ROWS * C_DIM;      // output 1: m (N,B)
    unsigned short* Wf = (unsigned short*)d_ws;       // 128 KB fragment-order W

    prep_kernel<<<M_ROWS / 256, 256, 0, stream>>>(mask, fg, W, Wf, m_out);
    mlp_kernel<<<M_ROWS / BM, 256, 0, stream>>>(x, Wf, b, m_out, out);
}

// Round 15
// 63.637 us; speedup vs baseline: 1.3384x; 1.0061x over previous
//
#include <hip/hip_runtime.h>
#include <hip/hip_bf16.h>

#define N_TOK 16384
#define B_DIM 8
#define C_DIM 256
#define M_ROWS (N_TOK * B_DIM)   // 131072
#define BM 32

typedef __attribute__((ext_vector_type(8))) short short8;
typedef __attribute__((ext_vector_type(4))) float f32x4;

__device__ __forceinline__ unsigned short f2bf(float f) {
    union { float f; unsigned u; } v; v.f = f;
    unsigned r = v.u + 0x7fffu + ((v.u >> 16) & 1u);  // RNE
    return (unsigned short)(r >> 16);
}

__device__ __forceinline__ float bf2f(unsigned short h) {
    union { unsigned u; float f; } v; v.u = ((unsigned)h) << 16;
    return v.f;
}

// packed RNE f32x2 -> bf16x2 (low = a, high = b)
__device__ __forceinline__ unsigned cvt_pk(float a, float b) {
    unsigned r;
    asm("v_cvt_pk_bf16_f32 %0, %1, %2" : "=v"(r) : "v"(a), "v"(b));
    return r;
}

// Kernel A: m -> d_out tail; W fp32 -> bf16 in MFMA-fragment order.
// Wf[((ctile*8 + k8)*64 + lane)*8 + r] = bf16(W[ctile*16 + (lane&15)][k8*32 + (lane>>4)*8 + r])
__global__ __launch_bounds__(256)
void prep_kernel(const int* __restrict__ mask, const int* __restrict__ fg,
                 const float* __restrict__ W, unsigned short* __restrict__ Wf,
                 float* __restrict__ m_out) {
    int i = blockIdx.x * 256 + threadIdx.x;
    if (i < C_DIM * C_DIM) {
        int d = i >> 8;            // W row = output col
        int c = i & 255;           // k
        int ctile = d >> 4;
        int k8    = c >> 5;
        int lane  = ((c >> 3) & 3) * 16 + (d & 15);
        int r     = c & 7;
        Wf[((ctile * 8 + k8) * 64 + lane) * 8 + r] = f2bf(W[i]);
    }
    if (i < M_ROWS) {
        int b = i & (B_DIM - 1);
        int n = i >> 3;
        m_out[i] = (fg[i] != 0) ? (1.0f - (float)mask[b * N_TOK + n]) : 0.0f;
    }
}

// Kernel B: r8 structure + SWAPPED mfma operands: acc = mfma(W_frag, x_frag)
// => C col=token, row=channel => lane holds 4 consecutive out-channels of one
// token => epilogue is 8 full float4 NONTEMPORAL stores (full 64B lines, no
// L3 allocation => x stays L3-resident across replays).
__global__ __launch_bounds__(256, 4)
void mlp_kernel(const float* __restrict__ x, const unsigned short* __restrict__ Wf,
                const float* __restrict__ bias, const float* __restrict__ m,
                float* __restrict__ out) {
    __shared__ unsigned short lds_x[BM * C_DIM];  // 16 KB bf16, XOR-swizzled

    const int t    = threadIdx.x;
    const int row0 = blockIdx.x * BM;

    // ---- Stage x tile (32 x 256 fp32 -> bf16 LDS), coalesced 32B/lane ----
    #pragma unroll
    for (int j = 0; j < 4; ++j) {
        int ci  = j * 256 + t;
        int row = ci >> 5;            // 0..31
        int cc  = (ci & 31) * 8;      // 0..248
        const float4* p = (const float4*)(x + (size_t)(row0 + row) * C_DIM + cc);
        float4 a0 = p[0];
        float4 a1 = p[1];
        int4 pk;
        pk.x = (int)cvt_pk(a0.x, a0.y);
        pk.y = (int)cvt_pk(a0.z, a0.w);
        pk.z = (int)cvt_pk(a1.x, a1.y);
        pk.w = (int)cvt_pk(a1.z, a1.w);
        int byte = (row * 512 + cc * 2) ^ ((row & 7) << 4);
        *(int4*)((char*)lds_x + byte) = pk;
    }
    __syncthreads();

    // ---- MFMA: 4 waves x 64 cols, 2(token-tile) x 4(channel-tile) ----
    const int lane = t & 63;
    const int wid  = t >> 6;
    const int col0 = wid * 64;
    const int lr   = lane & 15;
    const int kb   = (lane >> 4) * 8;
    const int rsub = (lane >> 4) * 4;

    // m per token (one token per lane), issued early
    float mv0 = m[row0 + lr];
    float mv1 = m[row0 + 16 + lr];

    f32x4 acc[2][4];
    #pragma unroll
    for (int i = 0; i < 2; ++i)
        #pragma unroll
        for (int j = 0; j < 4; ++j) acc[i][j] = (f32x4){0.f, 0.f, 0.f, 0.f};

    // Wave's fragment base: ctile = wid*4 + ct
    const short8* wfb = (const short8*)Wf + (size_t)wid * 4 * 8 * 64 + lane;

    short8 wcur[4], wnxt[4];
    #pragma unroll
    for (int ct = 0; ct < 4; ++ct)
        wcur[ct] = wfb[(ct * 8) * 64];            // k8 = 0, 1 KB coalesced/wave

    #pragma unroll
    for (int k8 = 0; k8 < 8; ++k8) {
        if (k8 < 7) {                              // 1-deep W prefetch from L2
            #pragma unroll
            for (int ct = 0; ct < 4; ++ct)
                wnxt[ct] = wfb[(ct * 8 + k8 + 1) * 64];
        }
        short8 af[2];
        #pragma unroll
        for (int rt = 0; rt < 2; ++rt) {
            int row  = rt * 16 + lr;
            int byte = (row * 512 + (k8 * 32 + kb) * 2) ^ ((row & 7) << 4);
            af[rt] = *(const short8*)((const char*)lds_x + byte);
        }
        // SWAPPED: A = W fragment (channels), B = x fragment (tokens)
        #pragma unroll
        for (int rt = 0; rt < 2; ++rt)
            #pragma unroll
            for (int ct = 0; ct < 4; ++ct)
                acc[rt][ct] = __builtin_amdgcn_mfma_f32_16x16x32_bf16(
                    wcur[ct], af[rt], acc[rt][ct], 0, 0, 0);
        #pragma unroll
        for (int ct = 0; ct < 4; ++ct) wcur[ct] = wnxt[ct];
    }

    // ---- Epilogue: lane = (token = rt*16+lr, channels ch0..ch0+3) ----
    float4 bv4[4];
    #pragma unroll
    for (int ct = 0; ct < 4; ++ct)
        bv4[ct] = *(const float4*)(bias + col0 + ct * 16 + rsub);

    #pragma unroll
    for (int rt = 0; rt < 2; ++rt) {
        const int token = rt * 16 + lr;
        const float mv  = rt ? mv1 : mv0;
        const int sz    = (token & 7) << 4;
        float* orow = out + (size_t)(row0 + token) * C_DIM;
        #pragma unroll
        for (int ct = 0; ct < 4; ++ct) {
            const int ch0 = col0 + ct * 16 + rsub;
            f32x4 y;
            y[0] = fmaxf(acc[rt][ct][0] + bv4[ct].x, 0.0f);
            y[1] = fmaxf(acc[rt][ct][1] + bv4[ct].y, 0.0f);
            y[2] = fmaxf(acc[rt][ct][2] + bv4[ct].z, 0.0f);
            y[3] = fmaxf(acc[rt][ct][3] + bv4[ct].w, 0.0f);
            if (mv == 0.0f) {
                ushort4 xs = *(const ushort4*)((const char*)lds_x +
                              ((token * 512 + ch0 * 2) ^ sz));
                y[0] = bf2f(xs.x); y[1] = bf2f(xs.y);
                y[2] = bf2f(xs.z); y[3] = bf2f(xs.w);
            }
            __builtin_nontemporal_store(y, (f32x4*)(orow + ch0));
        }
    }
}

extern "C" void kernel_launch(void* const* d_in, const int* in_sizes, int n_in,
                              void* d_out, int out_size, void* d_ws, size_t ws_size,
                              hipStream_t stream) {
    const float* x    = (const float*)d_in[0];
    const int*   mask = (const int*)d_in[1];
    const int*   fg   = (const int*)d_in[2];
    const float* W    = (const float*)d_in[3];
    const float* b    = (const float*)d_in[4];

    float* out   = (float*)d_out;
    float* m_out = out + (size_t)M_ROWS * C_DIM;      // output 1: m (N,B)
    unsigned short* Wf = (unsigned short*)d_ws;       // 128 KB fragment-order W

    prep_kernel<<<M_ROWS / 256, 256, 0, stream>>>(mask, fg, W, Wf, m_out);
    mlp_kernel<<<M_ROWS / BM, 256, 0, stream>>>(x, Wf, b, m_out, out);
}